// Round 1
// baseline (1384.749 us; speedup 1.0000x reference)
//
#include <hip/hip_runtime.h>

// LSTM_25512105738298: single-step LSTM + vocab projection + softmax on gfx950.
// Round 1: bf16 MFMA GEMMs (m97-style 128x128 tile, global_load_lds staging),
// fused pointwise LSTM, block-per-row softmax.

#define B_DIM 1024
#define I_DIM 1024
#define H_DIM 2048
#define G_DIM 8192      // 4*H
#define O_DIM 50257
#define O_PAD 50304     // 393 * 128

typedef __attribute__((ext_vector_type(4))) float fx4;
typedef __attribute__((ext_vector_type(8))) short s8;   // 8 x bf16 MFMA fragment
typedef __attribute__((ext_vector_type(4))) unsigned short ux4;

typedef const __attribute__((address_space(1))) void* gas_t;
typedef __attribute__((address_space(3))) void* las_t;

__device__ __forceinline__ unsigned short f2bf(float f) {
  unsigned int u = __float_as_uint(f);
  u += 0x7fffu + ((u >> 16) & 1u);   // RNE
  return (unsigned short)(u >> 16);
}

__device__ __forceinline__ void gload_lds16(const void* g, void* l) {
  __builtin_amdgcn_global_load_lds((gas_t)g, (las_t)l, 16, 0, 0);
}

// ---------------- conversions ----------------
__global__ __launch_bounds__(256) void cvt_bf16(const float* __restrict__ src,
                                                unsigned short* __restrict__ dst,
                                                int n4) {
  const int stride = gridDim.x * blockDim.x;
  for (int i = blockIdx.x * blockDim.x + threadIdx.x; i < n4; i += stride) {
    fx4 v = *(const fx4*)&src[(size_t)i * 4];
    ux4 o = { f2bf(v[0]), f2bf(v[1]), f2bf(v[2]), f2bf(v[3]) };
    *(ux4*)&dst[(size_t)i * 4] = o;
  }
}

__global__ __launch_bounds__(256) void cvt_wlin(const float* __restrict__ src,
                                                unsigned short* __restrict__ dst) {
  const int n4pad = (O_PAD / 4) * H_DIM;
  const int n4src = (O_DIM / 1) * (H_DIM / 4);
  const int stride = gridDim.x * blockDim.x;
  for (int i = blockIdx.x * blockDim.x + threadIdx.x; i < n4pad; i += stride) {
    ux4 o = { 0, 0, 0, 0 };
    if (i < n4src) {
      fx4 v = *(const fx4*)&src[(size_t)i * 4];
      o = { f2bf(v[0]), f2bf(v[1]), f2bf(v[2]), f2bf(v[3]) };
    }
    *(ux4*)&dst[(size_t)i * 4] = o;
  }
}

// ---------------- GEMM core: C[128x128] += A[128xK] * Bt[128xK]^T ----------------
// A row-major [M][K], Bt row-major [N][K] (i.e. C = A * B^T). 4 waves, each owns a
// 64x64 quadrant as 4x4 grid of 16x16 MFMA tiles. BK=64, two MFMA K-halves per step.
__device__ __forceinline__ void gemm_core(const unsigned short* __restrict__ A,
                                          const unsigned short* __restrict__ Bt,
                                          int K, int m0, int n0,
                                          unsigned short* lA, unsigned short* lB,
                                          fx4 (&acc)[4][4]) {
  const int tid  = threadIdx.x;
  const int lane = tid & 63;
  const int wid  = tid >> 6;
  const int wr   = (wid >> 1) * 64;
  const int wc   = (wid & 1) * 64;
  const int lrow = lane >> 3;        // row within 8-row staging chunk
  const int lcol = (lane & 7) * 8;   // element offset within row (16B granules)
  const int fr   = lane & 15;        // fragment row/col index
  const int fk   = (lane >> 4) * 8;  // fragment k-offset

  for (int kt = 0; kt < K; kt += 64) {
#pragma unroll
    for (int c = 0; c < 4; ++c) {
      const int chunk = wid * 4 + c;           // 16 chunks of 8 rows x 128B
      const int row = chunk * 8 + lrow;
      gload_lds16(A + (size_t)(m0 + row) * K + kt + lcol, &lA[chunk * 512]);
      gload_lds16(Bt + (size_t)(n0 + row) * K + kt + lcol, &lB[chunk * 512]);
    }
    __syncthreads();   // drains vmcnt for global_load_lds
#pragma unroll
    for (int kk = 0; kk < 64; kk += 32) {
      s8 af[4], bf[4];
#pragma unroll
      for (int t = 0; t < 4; ++t) {
        af[t] = *(const s8*)&lA[(wr + t * 16 + fr) * 64 + kk + fk];
        bf[t] = *(const s8*)&lB[(wc + t * 16 + fr) * 64 + kk + fk];
      }
#pragma unroll
      for (int i = 0; i < 4; ++i)
#pragma unroll
        for (int j = 0; j < 4; ++j)
          acc[i][j] = __builtin_amdgcn_mfma_f32_16x16x32_bf16(af[i], bf[j], acc[i][j], 0, 0, 0);
    }
    __syncthreads();
  }
}

// gates = x @ w_ih^T + h0 @ w_hh^T   (biases applied later in pointwise pass)
__global__ __launch_bounds__(256) void gates_gemm(const unsigned short* __restrict__ xb,
                                                  const unsigned short* __restrict__ wihb,
                                                  const unsigned short* __restrict__ h0b,
                                                  const unsigned short* __restrict__ whhb,
                                                  float* __restrict__ gates) {
  __shared__ __attribute__((aligned(16))) unsigned short lA[128 * 64];
  __shared__ __attribute__((aligned(16))) unsigned short lB[128 * 64];
  const int m0 = blockIdx.x * 128;
  const int n0 = blockIdx.y * 128;
  fx4 acc[4][4];
  const fx4 zero = { 0.f, 0.f, 0.f, 0.f };
#pragma unroll
  for (int i = 0; i < 4; ++i)
#pragma unroll
    for (int j = 0; j < 4; ++j) acc[i][j] = zero;

  gemm_core(xb, wihb, I_DIM, m0, n0, lA, lB, acc);
  gemm_core(h0b, whhb, H_DIM, m0, n0, lA, lB, acc);

  const int lane = threadIdx.x & 63;
  const int wid  = threadIdx.x >> 6;
  const int wr   = (wid >> 1) * 64;
  const int wc   = (wid & 1) * 64;
#pragma unroll
  for (int i = 0; i < 4; ++i) {
    const int row0 = m0 + wr + i * 16 + ((lane >> 4) << 2);
#pragma unroll
    for (int j = 0; j < 4; ++j) {
      const int col = n0 + wc + j * 16 + (lane & 15);
#pragma unroll
      for (int r = 0; r < 4; ++r)
        gates[(size_t)(row0 + r) * G_DIM + col] = acc[i][j][r];
    }
  }
}

// logits = hn @ w_lin^T + b_lin, written into d_out probs region (col < O_DIM)
__global__ __launch_bounds__(256) void logits_gemm(const unsigned short* __restrict__ hnb,
                                                   const unsigned short* __restrict__ wlinb,
                                                   const float* __restrict__ b_lin,
                                                   float* __restrict__ out) {
  __shared__ __attribute__((aligned(16))) unsigned short lA[128 * 64];
  __shared__ __attribute__((aligned(16))) unsigned short lB[128 * 64];
  const int m0 = blockIdx.x * 128;   // m fast-varying: 8 m-tiles share a B panel
  const int n0 = blockIdx.y * 128;
  fx4 acc[4][4];
  const fx4 zero = { 0.f, 0.f, 0.f, 0.f };
#pragma unroll
  for (int i = 0; i < 4; ++i)
#pragma unroll
    for (int j = 0; j < 4; ++j) acc[i][j] = zero;

  gemm_core(hnb, wlinb, H_DIM, m0, n0, lA, lB, acc);

  const int lane = threadIdx.x & 63;
  const int wid  = threadIdx.x >> 6;
  const int wr   = (wid >> 1) * 64;
  const int wc   = (wid & 1) * 64;
#pragma unroll
  for (int j = 0; j < 4; ++j) {
    const int col = n0 + wc + j * 16 + (lane & 15);
    if (col >= O_DIM) continue;
    const float bias = b_lin[col];
#pragma unroll
    for (int i = 0; i < 4; ++i) {
      const int row0 = m0 + wr + i * 16 + ((lane >> 4) << 2);
#pragma unroll
      for (int r = 0; r < 4; ++r)
        out[(size_t)(row0 + r) * O_DIM + col] = acc[i][j][r] + bias;
    }
  }
}

// ---------------- pointwise LSTM cell ----------------
__global__ __launch_bounds__(256) void lstm_pw(const float* __restrict__ gates,
                                               const float* __restrict__ c0,
                                               const float* __restrict__ b_ih,
                                               const float* __restrict__ b_hh,
                                               float* __restrict__ hn_out,
                                               float* __restrict__ cn_out,
                                               unsigned short* __restrict__ hn_bf) {
  const int n4 = (B_DIM * H_DIM) / 4;
  const int stride = gridDim.x * blockDim.x;
  for (int i = blockIdx.x * blockDim.x + threadIdx.x; i < n4; i += stride) {
    const int e = i * 4;
    const int b = e >> 11;           // / H_DIM
    const int h = e & (H_DIM - 1);
    const size_t gb = (size_t)b * G_DIM;
    fx4 ig = *(const fx4*)&gates[gb + h];
    fx4 fg = *(const fx4*)&gates[gb + H_DIM + h];
    fx4 gg = *(const fx4*)&gates[gb + 2 * H_DIM + h];
    fx4 og = *(const fx4*)&gates[gb + 3 * H_DIM + h];
    fx4 bi0 = *(const fx4*)&b_ih[h];
    fx4 bi1 = *(const fx4*)&b_ih[H_DIM + h];
    fx4 bi2 = *(const fx4*)&b_ih[2 * H_DIM + h];
    fx4 bi3 = *(const fx4*)&b_ih[3 * H_DIM + h];
    fx4 bh0 = *(const fx4*)&b_hh[h];
    fx4 bh1 = *(const fx4*)&b_hh[H_DIM + h];
    fx4 bh2 = *(const fx4*)&b_hh[2 * H_DIM + h];
    fx4 bh3 = *(const fx4*)&b_hh[3 * H_DIM + h];
    fx4 cv = *(const fx4*)&c0[(size_t)b * H_DIM + h];
    fx4 hnv, cnv;
    ux4 hb;
#pragma unroll
    for (int k = 0; k < 4; ++k) {
      const float iv = 1.f / (1.f + __expf(-(ig[k] + bi0[k] + bh0[k])));
      const float fv = 1.f / (1.f + __expf(-(fg[k] + bi1[k] + bh1[k])));
      const float gv = tanhf(gg[k] + bi2[k] + bh2[k]);
      const float ov = 1.f / (1.f + __expf(-(og[k] + bi3[k] + bh3[k])));
      const float cn_ = fv * cv[k] + iv * gv;
      const float hn_ = ov * tanhf(cn_);
      cnv[k] = cn_;
      hnv[k] = hn_;
      hb[k] = f2bf(hn_);
    }
    *(fx4*)&cn_out[(size_t)b * H_DIM + h] = cnv;
    *(fx4*)&hn_out[(size_t)b * H_DIM + h] = hnv;
    *(ux4*)&hn_bf[(size_t)b * H_DIM + h] = hb;
  }
}

// ---------------- softmax, one block per row, in place ----------------
__global__ __launch_bounds__(256) void softmax_rows(float* __restrict__ probs) {
  const int row = blockIdx.x;
  const int tid = threadIdx.x;
  float* x = probs + (size_t)row * O_DIM;

  float lm = -3.0e38f;
  for (int i = tid; i < O_DIM; i += 256) lm = fmaxf(lm, x[i]);
#pragma unroll
  for (int off = 32; off > 0; off >>= 1) lm = fmaxf(lm, __shfl_xor(lm, off, 64));
  __shared__ float sm[4], ss[4];
  if ((tid & 63) == 0) sm[tid >> 6] = lm;
  __syncthreads();
  const float rmax = fmaxf(fmaxf(sm[0], sm[1]), fmaxf(sm[2], sm[3]));

  float lsum = 0.f;
  for (int i = tid; i < O_DIM; i += 256) lsum += __expf(x[i] - rmax);
#pragma unroll
  for (int off = 32; off > 0; off >>= 1) lsum += __shfl_xor(lsum, off, 64);
  if ((tid & 63) == 0) ss[tid >> 6] = lsum;
  __syncthreads();
  const float rinv = 1.f / (ss[0] + ss[1] + ss[2] + ss[3]);

  for (int i = tid; i < O_DIM; i += 256) x[i] = __expf(x[i] - rmax) * rinv;
}

// ---------------- launcher ----------------
extern "C" void kernel_launch(void* const* d_in, const int* in_sizes, int n_in,
                              void* d_out, int out_size, void* d_ws, size_t ws_size,
                              hipStream_t stream) {
  const float* x_in  = (const float*)d_in[0];
  const float* h0    = (const float*)d_in[1];
  const float* c0    = (const float*)d_in[2];
  const float* w_ih  = (const float*)d_in[3];
  const float* w_hh  = (const float*)d_in[4];
  const float* b_ih  = (const float*)d_in[5];
  const float* b_hh  = (const float*)d_in[6];
  const float* w_lin = (const float*)d_in[7];
  const float* b_lin = (const float*)d_in[8];

  float* probs  = (float*)d_out;
  float* hn_out = probs + (size_t)B_DIM * O_DIM;
  float* cn_out = hn_out + (size_t)B_DIM * H_DIM;

  char* ws = (char*)d_ws;
  size_t off = 0;
  unsigned short* wlin_bf = (unsigned short*)(ws + off); off += (size_t)O_PAD * H_DIM * 2;  // 206 MB
  float*          gates   = (float*)(ws + off);          off += (size_t)B_DIM * G_DIM * 4;  //  33 MB
  unsigned short* in_bf   = (unsigned short*)(ws + off); off += (size_t)B_DIM * I_DIM * 2;
  unsigned short* h0_bf   = (unsigned short*)(ws + off); off += (size_t)B_DIM * H_DIM * 2;
  unsigned short* wih_bf  = (unsigned short*)(ws + off); off += (size_t)G_DIM * I_DIM * 2;
  unsigned short* whh_bf  = (unsigned short*)(ws + off); off += (size_t)G_DIM * H_DIM * 2;
  unsigned short* hn_bf   = (unsigned short*)(ws + off); off += (size_t)B_DIM * H_DIM * 2;

  cvt_wlin<<<2048, 256, 0, stream>>>(w_lin, wlin_bf);
  cvt_bf16<<<1024, 256, 0, stream>>>(x_in, in_bf, (B_DIM * I_DIM) / 4);
  cvt_bf16<<<1024, 256, 0, stream>>>(h0, h0_bf, (B_DIM * H_DIM) / 4);
  cvt_bf16<<<2048, 256, 0, stream>>>(w_ih, wih_bf, (G_DIM * I_DIM) / 4);
  cvt_bf16<<<2048, 256, 0, stream>>>(w_hh, whh_bf, (G_DIM * H_DIM) / 4);

  gates_gemm<<<dim3(8, 64), 256, 0, stream>>>(in_bf, wih_bf, h0_bf, whh_bf, gates);
  lstm_pw<<<1024, 256, 0, stream>>>(gates, c0, b_ih, b_hh, hn_out, cn_out, hn_bf);
  logits_gemm<<<dim3(8, 393), 256, 0, stream>>>(hn_bf, wlin_bf, b_lin, probs);
  softmax_rows<<<1024, 256, 0, stream>>>(probs);
}